// Round 13
// baseline (1205.343 us; speedup 1.0000x reference)
//
#include <hip/hip_runtime.h>

#define B_ 8
#define N_ 8192
#define S_ 1024
#define NS_ 64

typedef float v2f __attribute__((ext_vector_type(2)));
typedef unsigned long long u64;
typedef short bf16x8 __attribute__((ext_vector_type(8)));
typedef float f32x4 __attribute__((ext_vector_type(4)));

// out layout (floats)
#define OUT0 0                 // new_xyz (B,3,1024)
#define OUT1 24576             // new_points (B,128,1024)
#define OUT2 1073152           // new_seed (B,1024); fps int-bits until down_kernel converts

// ---------------------------------------------------------------------------
// DPP 64-lane reductions (row_shr 1/2/4/8, row_bcast 15/31; result lane 63).
// HW-validated on gfx950 in rounds 6-17.
// ---------------------------------------------------------------------------
template <int CTRL>
static __device__ __forceinline__ float dpp_max_step(float v) {
    int o = __builtin_amdgcn_update_dpp(__float_as_int(v), __float_as_int(v),
                                        CTRL, 0xf, 0xf, false);
    return fmaxf(v, __int_as_float(o));
}
static __device__ __forceinline__ float wave_max_f32(float v) {
    v = dpp_max_step<0x111>(v);
    v = dpp_max_step<0x112>(v);
    v = dpp_max_step<0x114>(v);
    v = dpp_max_step<0x118>(v);
    v = dpp_max_step<0x142>(v);
    v = dpp_max_step<0x143>(v);
    return __int_as_float(__builtin_amdgcn_readlane(__float_as_int(v), 63));
}
template <int CTRL>
static __device__ __forceinline__ unsigned dpp_umin_step(unsigned v) {
    unsigned o = (unsigned)__builtin_amdgcn_update_dpp((int)v, (int)v,
                                                       CTRL, 0xf, 0xf, false);
    return v < o ? v : o;
}
static __device__ __forceinline__ unsigned wave_min_u32(unsigned v) {
    v = dpp_umin_step<0x111>(v);
    v = dpp_umin_step<0x112>(v);
    v = dpp_umin_step<0x114>(v);
    v = dpp_umin_step<0x118>(v);
    v = dpp_umin_step<0x142>(v);
    v = dpp_umin_step<0x143>(v);
    return (unsigned)__builtin_amdgcn_readlane((int)v, 63);
}

// round-to-nearest-even f32 -> bf16 bits
static __device__ __forceinline__ short f2bf(float f) {
    unsigned u = __float_as_uint(f);
    return (short)((u + 0x7FFFu + ((u >> 16) & 1u)) >> 16);
}

// ---------------------------------------------------------------------------
// Kernel 1: farthest point sampling — R26 configuration, BEST MEASURED
// (fps ~985 us). One block/batch, 256 thr, J=16; cloud staged once into LDS
// float4[8192] (128 KB); step tail = slot ds_read -> 4x speculative
// broadcast ds_read_b128 of candidate coords, u64 compares resolve under
// LDS latency, cndmask select. oseed in LDS, dumped once.
// Structural map (all measured, do NOT retry):
//   R18 4-wave-alone -4% | R19/R20 multi-CU global sync ~4400 cy/step |
//   R21 LDS tag-spin/fused-u64 +100us | R22 inline-asm v_pk_* +154us |
//   R24 VGPR pin no-op; max3/b128 neutral | R25 two batches/CU -68% |
//   R8/R10 LDS inner-loop coords, R13/R14 concurrent fusion: negative.
// Remaining/step ~2300 cy = ~1470 issue (incl. AGPR shuttle) + ~830 latency.
// ---------------------------------------------------------------------------
#define FPS_T 256
#define FPS_J 16    // v2f per thread (32 points)

__global__ __launch_bounds__(FPS_T, 1) void fps_kernel(const float* __restrict__ xyz,
                                                       float* out) {
    const int b = blockIdx.x;
    const int t = threadIdx.x;          // 0..255
    const int lane = t & 63;
    const int wq = t >> 6;              // 0..3
    const float* X = xyz + b * 3 * N_;

    __shared__ float4 xyzq[N_];         // 128 KB staged cloud
    __shared__ u64 slots[8];            // [parity*4 + wave]
    __shared__ float seedL[S_];

    v2f px2[FPS_J], py2[FPS_J], pz2[FPS_J], dist2[FPS_J];
#pragma unroll
    for (int j = 0; j < FPS_J; ++j) {
        int n = t + 512 * j;            // .x -> n, .y -> n + 256
        float x0 = X[n],          x1 = X[n + 256];
        float y0 = X[N_ + n],     y1 = X[N_ + n + 256];
        float z0 = X[2 * N_ + n], z1 = X[2 * N_ + n + 256];
        px2[j] = (v2f){x0, x1};
        py2[j] = (v2f){y0, y1};
        pz2[j] = (v2f){z0, z1};
        dist2[j] = (v2f){1e10f, 1e10f};
        xyzq[n]       = make_float4(x0, y0, z0, 0.f);
        xyzq[n + 256] = make_float4(x1, y1, z1, 0.f);
    }
    __syncthreads();                    // staged cloud visible to all waves

    int ci = 0;
    float c0 = X[0], c1 = X[N_], c2 = X[2 * N_];

    for (int step = 0; step < S_; ++step) {
        if (t == 0) seedL[step] = __int_as_float(ci);

        v2f mv = (v2f){-1.0f, -1.0f};
        {
#pragma clang fp contract(off)
            v2f c0v = (v2f){c0, c0};
            v2f c1v = (v2f){c1, c1};
            v2f c2v = (v2f){c2, c2};
#pragma unroll
            for (int j = 0; j < FPS_J; ++j) {
                v2f e0 = px2[j] - c0v;
                v2f e1 = py2[j] - c1v;
                v2f e2 = pz2[j] - c2v;
                v2f q0 = e0 * e0;
                v2f q1 = e1 * e1;
                v2f q2 = e2 * e2;
                v2f d  = (q0 + q1) + q2;
                v2f dm = __builtin_elementwise_min(dist2[j], d);
                dist2[j] = dm;
                mv = __builtin_elementwise_max(mv, dm);
            }
        }
        float m = fmaxf(mv.x, mv.y);    // lane-local max of 32 elems

        unsigned mask = 0u;
#pragma unroll
        for (int j = 0; j < FPS_J; ++j) {
            if (dist2[j].x == m) mask |= (1u << (2 * j));
            if (dist2[j].y == m) mask |= (1u << (2 * j + 1));
        }
        float wmax = wave_max_f32(m);

        unsigned c = (unsigned)(__ffs(mask) - 1);   // mask != 0 always
        unsigned cand = (m == wmax) ? ((unsigned)t | (c << 8)) : 0xffffffffu;
        unsigned widx = wave_min_u32(cand);

        if (lane == 63) {
            u64 key = ((u64)__float_as_uint(wmax) << 13) | (u64)(8191u - widx);
            slots[((step & 1) << 2) + wq] = key;
        }
        __syncthreads();

        const u64* sp = &slots[(step & 1) << 2];
        u64 k0 = sp[0], k1 = sp[1], k2 = sp[2], k3 = sp[3];
        int i0 = 8191 - (int)(k0 & 0x1fffull);
        int i1 = 8191 - (int)(k1 & 0x1fffull);
        int i2 = 8191 - (int)(k2 & 0x1fffull);
        int i3 = 8191 - (int)(k3 & 0x1fffull);
        float4 p0 = xyzq[i0];
        float4 p1 = xyzq[i1];
        float4 p2 = xyzq[i2];
        float4 p3 = xyzq[i3];
        bool b01 = k0 > k1, b23 = k2 > k3;
        u64 ka = b01 ? k0 : k1;
        u64 kb = b23 ? k2 : k3;
        float4 pa, pb;
        pa.x = b01 ? p0.x : p1.x; pa.y = b01 ? p0.y : p1.y; pa.z = b01 ? p0.z : p1.z;
        pb.x = b23 ? p2.x : p3.x; pb.y = b23 ? p2.y : p3.y; pb.z = b23 ? p2.z : p3.z;
        bool bab = ka > kb;
        u64 km = bab ? ka : kb;
        ci = 8191 - (int)(km & 0x1fffull);
        c0 = bab ? pa.x : pb.x;
        c1 = bab ? pa.y : pb.y;
        c2 = bab ? pa.z : pb.z;
    }

    __syncthreads();                    // seedL fully written
    float* oseed = out + OUT2 + b * S_;
#pragma unroll
    for (int k = 0; k < 4; ++k)
        oseed[t + 256 * k] = seedL[t + 256 * k];
}

// ---------------------------------------------------------------------------
// Kernel 1b: one-shot weight conversion w1 (64x64) + w2 (128x64) -> bf16 in
// d_ws. Shared by all down_kernel blocks.
// ---------------------------------------------------------------------------
__global__ __launch_bounds__(256) void wconv_kernel(const float* __restrict__ w1,
                                                    const float* __restrict__ w2,
                                                    short* __restrict__ wbf) {
    int t = blockIdx.x * 256 + threadIdx.x;   // 0..12287
    float v = (t < 4096) ? w1[t] : w2[t - 4096];
    wbf[t] = f2bf(v);
}

// ---------------------------------------------------------------------------
// Kernel 2 (R28): fused downstream — one block per CENTROID PAIR, now 512
// threads / 8 waves (R27 was 256/4). Scan: each wave covers 1024 points
// (8 iters), testing BOTH centroids (load sharing kept from R27). MLP:
// waves 0-3 run centroid 0, waves 4-7 run centroid 1 — each group executes
// the verified 4-wave MFMA structure unchanged. Effects: 32 waves/CU
// (thread-capped, was 20 LDS-capped) for the latency-bound scan, scan
// critical path halved, MFMA parallelism doubled. LDS ~34 KB.
// Per-centroid arithmetic is op-for-op identical to R27/R16 => outputs
// bit-identical.
// ---------------------------------------------------------------------------
__global__ __launch_bounds__(512) void down_kernel(
    const float* __restrict__ xyz, const float* __restrict__ pts,
    const int* __restrict__ seed,
    const float* __restrict__ w0, const float* __restrict__ b0,
    const float* __restrict__ g0, const float* __restrict__ be0,
    const float* __restrict__ m0, const float* __restrict__ v0,
    const float* __restrict__ w1, const float* __restrict__ b1,
    const float* __restrict__ g1, const float* __restrict__ be1,
    const float* __restrict__ m1, const float* __restrict__ v1,
    const float* __restrict__ w2, const float* __restrict__ b2,
    const float* __restrict__ g2, const float* __restrict__ be2,
    const float* __restrict__ m2, const float* __restrict__ v2,
    float* out, const short* __restrict__ wbf) {
    const int sg = blockIdx.x;          // 0..4095
    const int b = sg >> 9, sp = sg & 511;
    const int s0 = sp << 1;             // centroids s0, s0+1
    const int t = threadIdx.x;          // 0..511
    const int lane = t & 63;
    const int w8 = __builtin_amdgcn_readfirstlane(t >> 6);   // wave 0..7
    const int wq = w8 & 3;              // wave within centroid group
    const int wcc = w8 >> 2;            // this wave's centroid for the MLP
    const int ln = lane & 15;
    const int quad = (lane >> 4) & 3;

    __shared__ float f0[2][64 * 9];
    __shared__ short feat[2][64 * 72];  // layer0 out; layer1 overwrites in place
    __shared__ float wmaxs[2][4 * 132];
    __shared__ float scs[256], ofs[256];
    __shared__ int cand[2][8 * 64];
    __shared__ int cnts[2][8];
    __shared__ int gis[2][64];

    const float* X = xyz + b * 3 * N_;

    // (a) broadcast read of both fps indices; centroid coords
    int ci0 = __float_as_int(out[OUT2 + b * S_ + s0]) & 8191;
    int ci1 = __float_as_int(out[OUT2 + b * S_ + s0 + 1]) & 8191;
    float cx0 = X[ci0], cy0 = X[N_ + ci0], cz0 = X[2 * N_ + ci0];
    float cx1 = X[ci1], cy1 = X[N_ + ci1], cz1 = X[2 * N_ + ci1];

    // per-channel BN fold (one sqrt+div per thread), shared by both centroids
    if (t < 192) {
        float sc, of;
        if (t < 64) {
            int c = t;
            sc = g0[c] / sqrtf(v0[c] + 1e-5f);
            of = (b0[c] - m0[c]) * sc + be0[c];
        } else if (t < 128) {
            int c = t - 64;
            sc = g1[c] / sqrtf(v1[c] + 1e-5f);
            of = (b1[c] - m1[c]) * sc + be1[c];
        } else {
            int c = t - 128;
            sc = g2[c] / sqrtf(v2[c] + 1e-5f);
            of = (b2[c] - m2[c]) * sc + be2[c];
        }
        scs[t] = sc;
        ofs[t] = of;
    }
    __syncthreads();   // all OUT2 reads complete (vmcnt drained) before overwrite

    if (t < 2) {
        int cc = t;
        int ci = cc ? ci1 : ci0;
        out[OUT0 + (b * 3 + 0) * S_ + s0 + cc] = cc ? cx1 : cx0;
        out[OUT0 + (b * 3 + 1) * S_ + s0 + cc] = cc ? cy1 : cy0;
        out[OUT0 + (b * 3 + 2) * S_ + s0 + cc] = cc ? cz1 : cz0;
        out[OUT2 + b * S_ + s0 + cc] = (float)seed[b * N_ + ci];
    }

    // (b) 8-wave ball query: wave w8 scans [1024*w8, +1024), 8 iters,
    // each point tested against BOTH centroids (loads shared).
    {
        int cnt0 = 0, cnt1 = 0;
        const int wbase = w8 << 10;
#pragma unroll 2
        for (int base = 0; base < 1024; base += 128) {
            int n0 = wbase + base + lane;
            int n1 = n0 + 64;
            float x0 = X[n0], y0 = X[N_ + n0], z0 = X[2 * N_ + n0];
            float x1 = X[n1], y1 = X[N_ + n1], z1 = X[2 * N_ + n1];

            float e0 = x0 - cx0, e1 = y0 - cy0, e2 = z0 - cz0;
            float dA0 = fmaf(e2, e2, fmaf(e1, e1, e0 * e0));
            float f0_ = x0 - cx1, f1_ = y0 - cy1, f2_ = z0 - cz1;
            float dB0 = fmaf(f2_, f2_, fmaf(f1_, f1_, f0_ * f0_));
            float q0 = x1 - cx0, q1 = y1 - cy0, q2 = z1 - cz0;
            float dA1 = fmaf(q2, q2, fmaf(q1, q1, q0 * q0));
            float r0 = x1 - cx1, r1 = y1 - cy1, r2 = z1 - cz1;
            float dB1 = fmaf(r2, r2, fmaf(r1, r1, r0 * r0));

            u64 mA0 = __ballot(dA0 <= 0.04f);
            if (mA0) {
                int pos = cnt0 + (int)__popcll(mA0 & ((1ull << lane) - 1ull));
                if ((dA0 <= 0.04f) && pos < NS_) cand[0][(w8 << 6) + pos] = n0;
                cnt0 += (int)__popcll(mA0);
            }
            u64 mB0 = __ballot(dB0 <= 0.04f);
            if (mB0) {
                int pos = cnt1 + (int)__popcll(mB0 & ((1ull << lane) - 1ull));
                if ((dB0 <= 0.04f) && pos < NS_) cand[1][(w8 << 6) + pos] = n0;
                cnt1 += (int)__popcll(mB0);
            }
            u64 mA1 = __ballot(dA1 <= 0.04f);
            if (mA1) {
                int pos = cnt0 + (int)__popcll(mA1 & ((1ull << lane) - 1ull));
                if ((dA1 <= 0.04f) && pos < NS_) cand[0][(w8 << 6) + pos] = n1;
                cnt0 += (int)__popcll(mA1);
            }
            u64 mB1 = __ballot(dB1 <= 0.04f);
            if (mB1) {
                int pos = cnt1 + (int)__popcll(mB1 & ((1ull << lane) - 1ull));
                if ((dB1 <= 0.04f) && pos < NS_) cand[1][(w8 << 6) + pos] = n1;
                cnt1 += (int)__popcll(mB1);
            }
        }
        if (lane == 0) { cnts[0][w8] = cnt0; cnts[1][w8] = cnt1; }
    }
    __syncthreads();

    // merge per centroid: first 64 in global ascending index order
    // (wave segments [1024w, +1024) are index-ordered; within-wave append
    // order is ascending — same semantics as R27).
    if (t < 128) {
        int cc = t >> 6, k = t & 63;
        int start = 0, sel = -1, firstv = -1;
#pragma unroll
        for (int w = 0; w < 8; ++w) {
            int cw = min(cnts[cc][w], NS_);
            if (firstv < 0 && cw > 0) firstv = cand[cc][(w << 6)];
            if (sel < 0 && k < start + cw) sel = cand[cc][(w << 6) + (k - start)];
            start += cw;
        }
        if (sel < 0) sel = firstv;
        gis[cc][k] = sel;
    }
    __syncthreads();

    if (t < 128) {
        int cc = t >> 6, k = t & 63;
        int gidx = gis[cc][k] & 8191;
        const float* P = pts + b * 3 * N_;
        float ccx = cc ? cx1 : cx0;
        float ccy = cc ? cy1 : cy0;
        float ccz = cc ? cz1 : cz0;
        f0[cc][k * 9 + 0] = X[gidx] - ccx;
        f0[cc][k * 9 + 1] = X[N_ + gidx] - ccy;
        f0[cc][k * 9 + 2] = X[2 * N_ + gidx] - ccz;
        f0[cc][k * 9 + 3] = P[gidx];
        f0[cc][k * 9 + 4] = P[N_ + gidx];
        f0[cc][k * 9 + 5] = P[2 * N_ + gidx];
    }
    __syncthreads();

    // (c) layer 0: 6 -> 64 on VALU; point = lane; wave group wcc handles
    // its centroid, wave wq owns a 16-channel slice.
    {
        float in[6];
#pragma unroll
        for (int c = 0; c < 6; ++c) in[c] = f0[wcc][lane * 9 + c];
#pragma unroll 1
        for (int i = 0; i < 16; i += 4) {
            int o = wq * 16 + i;
            float a0 = 0.f, a1 = 0.f, a2 = 0.f, a3 = 0.f;
#pragma unroll
            for (int c = 0; c < 6; ++c) {
                float rc = in[c];
                a0 = fmaf(rc, w0[(o + 0) * 6 + c], a0);
                a1 = fmaf(rc, w0[(o + 1) * 6 + c], a1);
                a2 = fmaf(rc, w0[(o + 2) * 6 + c], a2);
                a3 = fmaf(rc, w0[(o + 3) * 6 + c], a3);
            }
            feat[wcc][lane * 72 + o + 0] = f2bf(fmaxf(fmaf(a0, scs[o + 0], ofs[o + 0]), 0.f));
            feat[wcc][lane * 72 + o + 1] = f2bf(fmaxf(fmaf(a1, scs[o + 1], ofs[o + 1]), 0.f));
            feat[wcc][lane * 72 + o + 2] = f2bf(fmaxf(fmaf(a2, scs[o + 2], ofs[o + 2]), 0.f));
            feat[wcc][lane * 72 + o + 3] = f2bf(fmaxf(fmaf(a3, scs[o + 3], ofs[o + 3]), 0.f));
        }
    }
    __syncthreads();

    const int arow = 16 * wq + ln;   // this wave's m-tile row for A-frags
    const bool usebf = (wbf != nullptr);

    // layer 1: 64 -> 64 via MFMA (4 ntiles x 2 ksteps), group wcc on its
    // centroid. In-place feat write: each wave reads/writes only its own
    // 16-row block of feat[wcc] (same-wave DS order).
    {
        bf16x8 a1f[2];
#pragma unroll
        for (int ks = 0; ks < 2; ++ks)
            a1f[ks] = *(const bf16x8*)&feat[wcc][arow * 72 + ks * 32 + quad * 8];

#pragma unroll
        for (int nt = 0; nt < 4; ++nt) {
            f32x4 acc = {0.f, 0.f, 0.f, 0.f};
#pragma unroll
            for (int ks = 0; ks < 2; ++ks) {
                int off = (nt * 16 + ln) * 64 + ks * 32 + quad * 8;
                bf16x8 bf;
                if (usebf) {
                    bf = *(const bf16x8*)&wbf[off];
                } else {
                    const float* wr = w1 + off;
                    float4 p = *(const float4*)wr;
                    float4 q = *(const float4*)(wr + 4);
                    bf = (bf16x8){f2bf(p.x), f2bf(p.y), f2bf(p.z), f2bf(p.w),
                                  f2bf(q.x), f2bf(q.y), f2bf(q.z), f2bf(q.w)};
                }
                acc = __builtin_amdgcn_mfma_f32_16x16x32_bf16(a1f[ks], bf, acc, 0, 0, 0);
            }
            int o = nt * 16 + ln;
            float sc = scs[64 + o], of = ofs[64 + o];
#pragma unroll
            for (int reg = 0; reg < 4; ++reg) {
                float y = fmaxf(fmaf(acc[reg], sc, of), 0.f);
                feat[wcc][(16 * wq + quad * 4 + reg) * 72 + o] = f2bf(y);
            }
        }
    }
    // no barrier: each wave reads back only its own m-tile rows

    // layer 2: 64 -> 128 via MFMA (8 ntiles x 2 ksteps) + fused k-max
    {
        bf16x8 a2f[2];
#pragma unroll
        for (int ks = 0; ks < 2; ++ks)
            a2f[ks] = *(const bf16x8*)&feat[wcc][arow * 72 + ks * 32 + quad * 8];

#pragma unroll
        for (int nt = 0; nt < 8; ++nt) {
            f32x4 acc = {0.f, 0.f, 0.f, 0.f};
#pragma unroll
            for (int ks = 0; ks < 2; ++ks) {
                int off = (nt * 16 + ln) * 64 + ks * 32 + quad * 8;
                bf16x8 bf;
                if (usebf) {
                    bf = *(const bf16x8*)&wbf[4096 + off];
                } else {
                    const float* wr = w2 + off;
                    float4 p = *(const float4*)wr;
                    float4 q = *(const float4*)(wr + 4);
                    bf = (bf16x8){f2bf(p.x), f2bf(p.y), f2bf(p.z), f2bf(p.w),
                                  f2bf(q.x), f2bf(q.y), f2bf(q.z), f2bf(q.w)};
                }
                acc = __builtin_amdgcn_mfma_f32_16x16x32_bf16(a2f[ks], bf, acc, 0, 0, 0);
            }
            int o = nt * 16 + ln;
            float sc = scs[128 + o], of = ofs[128 + o];
            float m = -1.f;
#pragma unroll
            for (int reg = 0; reg < 4; ++reg) {
                float y = fmaxf(fmaf(acc[reg], sc, of), 0.f);
                m = fmaxf(m, y);
            }
            m = fmaxf(m, __shfl_xor(m, 16, 64));
            m = fmaxf(m, __shfl_xor(m, 32, 64));
            if (lane < 16) wmaxs[wcc][wq * 132 + o] = m;
        }
    }
    __syncthreads();

    // final: max over the 4 waves' m-tiles, store new_points for both
    if (t < 256) {
        int cc = t >> 7, ch = t & 127;
        float m = fmaxf(fmaxf(wmaxs[cc][0 * 132 + ch], wmaxs[cc][1 * 132 + ch]),
                        fmaxf(wmaxs[cc][2 * 132 + ch], wmaxs[cc][3 * 132 + ch]));
        out[OUT1 + (b * 128 + ch) * S_ + s0 + cc] = m;
    }
}

extern "C" void kernel_launch(void* const* d_in, const int* in_sizes, int n_in,
                              void* d_out, int out_size, void* d_ws, size_t ws_size,
                              hipStream_t stream) {
    const float* xyz  = (const float*)d_in[0];
    const float* pts  = (const float*)d_in[1];
    const int*   seed = (const int*)d_in[2];
    const float* w0 = (const float*)d_in[3];
    const float* b0 = (const float*)d_in[4];
    const float* g0 = (const float*)d_in[5];
    const float* be0 = (const float*)d_in[6];
    const float* m0 = (const float*)d_in[7];
    const float* v0 = (const float*)d_in[8];
    const float* w1 = (const float*)d_in[9];
    const float* b1 = (const float*)d_in[10];
    const float* g1 = (const float*)d_in[11];
    const float* be1 = (const float*)d_in[12];
    const float* m1 = (const float*)d_in[13];
    const float* v1 = (const float*)d_in[14];
    const float* w2 = (const float*)d_in[15];
    const float* b2 = (const float*)d_in[16];
    const float* g2 = (const float*)d_in[17];
    const float* be2 = (const float*)d_in[18];
    const float* m2 = (const float*)d_in[19];
    const float* v2 = (const float*)d_in[20];
    float* out = (float*)d_out;

    short* wbf = nullptr;
    if (ws_size >= 12288 * sizeof(short)) {
        wbf = (short*)d_ws;
        wconv_kernel<<<dim3(48), dim3(256), 0, stream>>>(w1, w2, wbf);
    }

    fps_kernel<<<dim3(B_), dim3(FPS_T), 0, stream>>>(xyz, out);
    down_kernel<<<dim3(B_ * S_ / 2), dim3(512), 0, stream>>>(xyz, pts, seed,
        w0, b0, g0, be0, m0, v0,
        w1, b1, g1, be1, m1, v1,
        w2, b2, g2, be2, m2, v2,
        out, wbf);
}

// Round 14
// 1167.479 us; speedup vs baseline: 1.0324x; 1.0324x over previous
//
#include <hip/hip_runtime.h>

#define B_ 8
#define N_ 8192
#define S_ 1024
#define NS_ 64

typedef float v2f __attribute__((ext_vector_type(2)));
typedef unsigned long long u64;
typedef short bf16x8 __attribute__((ext_vector_type(8)));
typedef float f32x4 __attribute__((ext_vector_type(4)));

// out layout (floats)
#define OUT0 0                 // new_xyz (B,3,1024)
#define OUT1 24576             // new_points (B,128,1024)
#define OUT2 1073152           // new_seed (B,1024); fps int-bits until down_kernel converts

// ---------------------------------------------------------------------------
// DPP 64-lane reductions (row_shr 1/2/4/8, row_bcast 15/31; result lane 63).
// HW-validated on gfx950 in rounds 6-17.
// ---------------------------------------------------------------------------
template <int CTRL>
static __device__ __forceinline__ float dpp_max_step(float v) {
    int o = __builtin_amdgcn_update_dpp(__float_as_int(v), __float_as_int(v),
                                        CTRL, 0xf, 0xf, false);
    return fmaxf(v, __int_as_float(o));
}
static __device__ __forceinline__ float wave_max_f32(float v) {
    v = dpp_max_step<0x111>(v);
    v = dpp_max_step<0x112>(v);
    v = dpp_max_step<0x114>(v);
    v = dpp_max_step<0x118>(v);
    v = dpp_max_step<0x142>(v);
    v = dpp_max_step<0x143>(v);
    return __int_as_float(__builtin_amdgcn_readlane(__float_as_int(v), 63));
}
template <int CTRL>
static __device__ __forceinline__ unsigned dpp_umin_step(unsigned v) {
    unsigned o = (unsigned)__builtin_amdgcn_update_dpp((int)v, (int)v,
                                                       CTRL, 0xf, 0xf, false);
    return v < o ? v : o;
}
static __device__ __forceinline__ unsigned wave_min_u32(unsigned v) {
    v = dpp_umin_step<0x111>(v);
    v = dpp_umin_step<0x112>(v);
    v = dpp_umin_step<0x114>(v);
    v = dpp_umin_step<0x118>(v);
    v = dpp_umin_step<0x142>(v);
    v = dpp_umin_step<0x143>(v);
    return (unsigned)__builtin_amdgcn_readlane((int)v, 63);
}

// round-to-nearest-even f32 -> bf16 bits
static __device__ __forceinline__ short f2bf(float f) {
    unsigned u = __float_as_uint(f);
    return (short)((u + 0x7FFFu + ((u >> 16) & 1u)) >> 16);
}

// ---------------------------------------------------------------------------
// Kernel 1: farthest point sampling — R26 configuration, BEST MEASURED
// (fps ~985-990 us). One block/batch, 256 thr, J=16; cloud staged once into
// LDS float4[8192] (128 KB); step tail = slot ds_read -> 4x speculative
// broadcast ds_read_b128 of candidate coords, u64 compares resolve under
// LDS latency, cndmask select. oseed in LDS, dumped once.
// Structural map (all measured, do NOT retry):
//   R18 4-wave-alone -4% | R19/R20 multi-CU global sync ~4400 cy/step |
//   R21 LDS tag-spin/fused-u64 +100us | R22 inline-asm v_pk_* +154us |
//   R24 VGPR pin no-op; max3/b128 neutral | R25 two batches/CU -68% |
//   R8/R10 LDS inner-loop coords, R13/R14 concurrent fusion: negative.
// Remaining/step ~2300 cy = ~1470 issue (incl. AGPR shuttle) + ~830 latency.
// ---------------------------------------------------------------------------
#define FPS_T 256
#define FPS_J 16    // v2f per thread (32 points)

__global__ __launch_bounds__(FPS_T, 1) void fps_kernel(const float* __restrict__ xyz,
                                                       float* out) {
    const int b = blockIdx.x;
    const int t = threadIdx.x;          // 0..255
    const int lane = t & 63;
    const int wq = t >> 6;              // 0..3
    const float* X = xyz + b * 3 * N_;

    __shared__ float4 xyzq[N_];         // 128 KB staged cloud
    __shared__ u64 slots[8];            // [parity*4 + wave]
    __shared__ float seedL[S_];

    v2f px2[FPS_J], py2[FPS_J], pz2[FPS_J], dist2[FPS_J];
#pragma unroll
    for (int j = 0; j < FPS_J; ++j) {
        int n = t + 512 * j;            // .x -> n, .y -> n + 256
        float x0 = X[n],          x1 = X[n + 256];
        float y0 = X[N_ + n],     y1 = X[N_ + n + 256];
        float z0 = X[2 * N_ + n], z1 = X[2 * N_ + n + 256];
        px2[j] = (v2f){x0, x1};
        py2[j] = (v2f){y0, y1};
        pz2[j] = (v2f){z0, z1};
        dist2[j] = (v2f){1e10f, 1e10f};
        xyzq[n]       = make_float4(x0, y0, z0, 0.f);
        xyzq[n + 256] = make_float4(x1, y1, z1, 0.f);
    }
    __syncthreads();                    // staged cloud visible to all waves

    int ci = 0;
    float c0 = X[0], c1 = X[N_], c2 = X[2 * N_];

    for (int step = 0; step < S_; ++step) {
        if (t == 0) seedL[step] = __int_as_float(ci);

        v2f mv = (v2f){-1.0f, -1.0f};
        {
#pragma clang fp contract(off)
            v2f c0v = (v2f){c0, c0};
            v2f c1v = (v2f){c1, c1};
            v2f c2v = (v2f){c2, c2};
#pragma unroll
            for (int j = 0; j < FPS_J; ++j) {
                v2f e0 = px2[j] - c0v;
                v2f e1 = py2[j] - c1v;
                v2f e2 = pz2[j] - c2v;
                v2f q0 = e0 * e0;
                v2f q1 = e1 * e1;
                v2f q2 = e2 * e2;
                v2f d  = (q0 + q1) + q2;
                v2f dm = __builtin_elementwise_min(dist2[j], d);
                dist2[j] = dm;
                mv = __builtin_elementwise_max(mv, dm);
            }
        }
        float m = fmaxf(mv.x, mv.y);    // lane-local max of 32 elems

        unsigned mask = 0u;
#pragma unroll
        for (int j = 0; j < FPS_J; ++j) {
            if (dist2[j].x == m) mask |= (1u << (2 * j));
            if (dist2[j].y == m) mask |= (1u << (2 * j + 1));
        }
        float wmax = wave_max_f32(m);

        unsigned c = (unsigned)(__ffs(mask) - 1);   // mask != 0 always
        unsigned cand = (m == wmax) ? ((unsigned)t | (c << 8)) : 0xffffffffu;
        unsigned widx = wave_min_u32(cand);

        if (lane == 63) {
            u64 key = ((u64)__float_as_uint(wmax) << 13) | (u64)(8191u - widx);
            slots[((step & 1) << 2) + wq] = key;
        }
        __syncthreads();

        const u64* sp = &slots[(step & 1) << 2];
        u64 k0 = sp[0], k1 = sp[1], k2 = sp[2], k3 = sp[3];
        int i0 = 8191 - (int)(k0 & 0x1fffull);
        int i1 = 8191 - (int)(k1 & 0x1fffull);
        int i2 = 8191 - (int)(k2 & 0x1fffull);
        int i3 = 8191 - (int)(k3 & 0x1fffull);
        float4 p0 = xyzq[i0];
        float4 p1 = xyzq[i1];
        float4 p2 = xyzq[i2];
        float4 p3 = xyzq[i3];
        bool b01 = k0 > k1, b23 = k2 > k3;
        u64 ka = b01 ? k0 : k1;
        u64 kb = b23 ? k2 : k3;
        float4 pa, pb;
        pa.x = b01 ? p0.x : p1.x; pa.y = b01 ? p0.y : p1.y; pa.z = b01 ? p0.z : p1.z;
        pb.x = b23 ? p2.x : p3.x; pb.y = b23 ? p2.y : p3.y; pb.z = b23 ? p2.z : p3.z;
        bool bab = ka > kb;
        u64 km = bab ? ka : kb;
        ci = 8191 - (int)(km & 0x1fffull);
        c0 = bab ? pa.x : pb.x;
        c1 = bab ? pa.y : pb.y;
        c2 = bab ? pa.z : pb.z;
    }

    __syncthreads();                    // seedL fully written
    float* oseed = out + OUT2 + b * S_;
#pragma unroll
    for (int k = 0; k < 4; ++k)
        oseed[t + 256 * k] = seedL[t + 256 * k];
}

// ---------------------------------------------------------------------------
// Kernel 1b: one-shot weight conversion w1 (64x64) + w2 (128x64) -> bf16 in
// d_ws. Shared by all down_kernel blocks.
// ---------------------------------------------------------------------------
__global__ __launch_bounds__(256) void wconv_kernel(const float* __restrict__ w1,
                                                    const float* __restrict__ w2,
                                                    short* __restrict__ wbf) {
    int t = blockIdx.x * 256 + threadIdx.x;   // 0..12287
    float v = (t < 4096) ? w1[t] : w2[t - 4096];
    wbf[t] = f2bf(v);
}

// ---------------------------------------------------------------------------
// Kernel 2 (R27 — REVERT of R28): fused downstream, one block (256 thr) per
// CENTROID PAIR (4096 blocks). Ball-query scan loads each point once, tests
// both centroids; MFMA weight fragments feed TWO MFMAs; BN fold (ALL 256
// threads — R28's t<192 guard left scs[192..256) uninitialized, absmax
// 4.69), barriers, dispatch amortized 2x.
// R28 ledger: 512-thr/8-wave pair block = -37 us (loses dual-MFMA weight
// sharing, more barrier cost; down is NOT TLP-starved) + the scs bug.
// Do not retry wider blocks.
// ---------------------------------------------------------------------------
__global__ __launch_bounds__(256) void down_kernel(
    const float* __restrict__ xyz, const float* __restrict__ pts,
    const int* __restrict__ seed,
    const float* __restrict__ w0, const float* __restrict__ b0,
    const float* __restrict__ g0, const float* __restrict__ be0,
    const float* __restrict__ m0, const float* __restrict__ v0,
    const float* __restrict__ w1, const float* __restrict__ b1,
    const float* __restrict__ g1, const float* __restrict__ be1,
    const float* __restrict__ m1, const float* __restrict__ v1,
    const float* __restrict__ w2, const float* __restrict__ b2,
    const float* __restrict__ g2, const float* __restrict__ be2,
    const float* __restrict__ m2, const float* __restrict__ v2,
    float* out, const short* __restrict__ wbf) {
    const int sg = blockIdx.x;          // 0..4095
    const int b = sg >> 9, sp = sg & 511;
    const int s0 = sp << 1;             // centroids s0, s0+1
    const int t = threadIdx.x;
    const int lane = t & 63;
    const int wq = __builtin_amdgcn_readfirstlane(t >> 6);   // 0..3
    const int ln = lane & 15;
    const int quad = (lane >> 4) & 3;

    __shared__ float f0[2][64 * 9];
    __shared__ short feat[2][64 * 72];  // layer0 out; layer1 overwrites in place
    __shared__ float wmaxs[2][4 * 132];
    __shared__ float scs[256], ofs[256];
    __shared__ int cand[2][4 * 64];
    __shared__ int cnts[2][4];
    __shared__ int gis[2][64];

    const float* X = xyz + b * 3 * N_;

    // (a) broadcast read of both fps indices; centroid coords
    int ci0 = __float_as_int(out[OUT2 + b * S_ + s0]) & 8191;
    int ci1 = __float_as_int(out[OUT2 + b * S_ + s0 + 1]) & 8191;
    float cx0 = X[ci0], cy0 = X[N_ + ci0], cz0 = X[2 * N_ + ci0];
    float cx1 = X[ci1], cy1 = X[N_ + ci1], cz1 = X[2 * N_ + ci1];

    // per-channel BN fold (one sqrt+div per thread), shared by both centroids
    {
        float sc, of;
        if (t < 64) {
            int c = t;
            sc = g0[c] / sqrtf(v0[c] + 1e-5f);
            of = (b0[c] - m0[c]) * sc + be0[c];
        } else if (t < 128) {
            int c = t - 64;
            sc = g1[c] / sqrtf(v1[c] + 1e-5f);
            of = (b1[c] - m1[c]) * sc + be1[c];
        } else {
            int c = t - 128;
            sc = g2[c] / sqrtf(v2[c] + 1e-5f);
            of = (b2[c] - m2[c]) * sc + be2[c];
        }
        scs[t] = sc;
        ofs[t] = of;
    }
    __syncthreads();   // all OUT2 reads complete (vmcnt drained) before overwrite

    if (t < 2) {
        int cc = t;
        int ci = cc ? ci1 : ci0;
        out[OUT0 + (b * 3 + 0) * S_ + s0 + cc] = cc ? cx1 : cx0;
        out[OUT0 + (b * 3 + 1) * S_ + s0 + cc] = cc ? cy1 : cy0;
        out[OUT0 + (b * 3 + 2) * S_ + s0 + cc] = cc ? cz1 : cz0;
        out[OUT2 + b * S_ + s0 + cc] = (float)seed[b * N_ + ci];
    }

    // (b) 4-wave ball query: wave wq scans [2048*wq, +2048), 16 iters,
    // each point tested against BOTH centroids (loads shared).
    {
        int cnt0 = 0, cnt1 = 0;
        const int wbase = wq << 11;
#pragma unroll 2
        for (int base = 0; base < 2048; base += 128) {
            int n0 = wbase + base + lane;
            int n1 = n0 + 64;
            float x0 = X[n0], y0 = X[N_ + n0], z0 = X[2 * N_ + n0];
            float x1 = X[n1], y1 = X[N_ + n1], z1 = X[2 * N_ + n1];

            float e0 = x0 - cx0, e1 = y0 - cy0, e2 = z0 - cz0;
            float dA0 = fmaf(e2, e2, fmaf(e1, e1, e0 * e0));
            float f0_ = x0 - cx1, f1_ = y0 - cy1, f2_ = z0 - cz1;
            float dB0 = fmaf(f2_, f2_, fmaf(f1_, f1_, f0_ * f0_));
            float q0 = x1 - cx0, q1 = y1 - cy0, q2 = z1 - cz0;
            float dA1 = fmaf(q2, q2, fmaf(q1, q1, q0 * q0));
            float r0 = x1 - cx1, r1 = y1 - cy1, r2 = z1 - cz1;
            float dB1 = fmaf(r2, r2, fmaf(r1, r1, r0 * r0));

            u64 mA0 = __ballot(dA0 <= 0.04f);
            if (mA0) {
                int pos = cnt0 + (int)__popcll(mA0 & ((1ull << lane) - 1ull));
                if ((dA0 <= 0.04f) && pos < NS_) cand[0][(wq << 6) + pos] = n0;
                cnt0 += (int)__popcll(mA0);
            }
            u64 mB0 = __ballot(dB0 <= 0.04f);
            if (mB0) {
                int pos = cnt1 + (int)__popcll(mB0 & ((1ull << lane) - 1ull));
                if ((dB0 <= 0.04f) && pos < NS_) cand[1][(wq << 6) + pos] = n0;
                cnt1 += (int)__popcll(mB0);
            }
            u64 mA1 = __ballot(dA1 <= 0.04f);
            if (mA1) {
                int pos = cnt0 + (int)__popcll(mA1 & ((1ull << lane) - 1ull));
                if ((dA1 <= 0.04f) && pos < NS_) cand[0][(wq << 6) + pos] = n1;
                cnt0 += (int)__popcll(mA1);
            }
            u64 mB1 = __ballot(dB1 <= 0.04f);
            if (mB1) {
                int pos = cnt1 + (int)__popcll(mB1 & ((1ull << lane) - 1ull));
                if ((dB1 <= 0.04f) && pos < NS_) cand[1][(wq << 6) + pos] = n1;
                cnt1 += (int)__popcll(mB1);
            }
        }
        if (lane == 0) { cnts[0][wq] = cnt0; cnts[1][wq] = cnt1; }
    }
    __syncthreads();

    // merge per centroid: first 64 in global ascending index order
    if (t < 128) {
        int cc = t >> 6, k = t & 63;
        int start = 0, sel = -1, firstv = -1;
#pragma unroll
        for (int w = 0; w < 4; ++w) {
            int cw = min(cnts[cc][w], NS_);
            if (firstv < 0 && cw > 0) firstv = cand[cc][(w << 6)];
            if (sel < 0 && k < start + cw) sel = cand[cc][(w << 6) + (k - start)];
            start += cw;
        }
        if (sel < 0) sel = firstv;
        gis[cc][k] = sel;
    }
    __syncthreads();

    if (t < 128) {
        int cc = t >> 6, k = t & 63;
        int gidx = gis[cc][k] & 8191;
        const float* P = pts + b * 3 * N_;
        float ccx = cc ? cx1 : cx0;
        float ccy = cc ? cy1 : cy0;
        float ccz = cc ? cz1 : cz0;
        f0[cc][k * 9 + 0] = X[gidx] - ccx;
        f0[cc][k * 9 + 1] = X[N_ + gidx] - ccy;
        f0[cc][k * 9 + 2] = X[2 * N_ + gidx] - ccz;
        f0[cc][k * 9 + 3] = P[gidx];
        f0[cc][k * 9 + 4] = P[N_ + gidx];
        f0[cc][k * 9 + 5] = P[2 * N_ + gidx];
    }
    __syncthreads();

    // (c) layer 0: 6 -> 64 on VALU; point = lane, wave owns 16-channel slice;
    // both centroids done by every thread (weights shared).
#pragma unroll 1
    for (int cc = 0; cc < 2; ++cc) {
        float in[6];
#pragma unroll
        for (int c = 0; c < 6; ++c) in[c] = f0[cc][lane * 9 + c];
#pragma unroll 1
        for (int i = 0; i < 16; i += 4) {
            int o = wq * 16 + i;
            float a0 = 0.f, a1 = 0.f, a2 = 0.f, a3 = 0.f;
#pragma unroll
            for (int c = 0; c < 6; ++c) {
                float rc = in[c];
                a0 = fmaf(rc, w0[(o + 0) * 6 + c], a0);
                a1 = fmaf(rc, w0[(o + 1) * 6 + c], a1);
                a2 = fmaf(rc, w0[(o + 2) * 6 + c], a2);
                a3 = fmaf(rc, w0[(o + 3) * 6 + c], a3);
            }
            feat[cc][lane * 72 + o + 0] = f2bf(fmaxf(fmaf(a0, scs[o + 0], ofs[o + 0]), 0.f));
            feat[cc][lane * 72 + o + 1] = f2bf(fmaxf(fmaf(a1, scs[o + 1], ofs[o + 1]), 0.f));
            feat[cc][lane * 72 + o + 2] = f2bf(fmaxf(fmaf(a2, scs[o + 2], ofs[o + 2]), 0.f));
            feat[cc][lane * 72 + o + 3] = f2bf(fmaxf(fmaf(a3, scs[o + 3], ofs[o + 3]), 0.f));
        }
    }
    __syncthreads();

    const int arow = 16 * wq + ln;   // this wave's m-tile row for A-frags
    const bool usebf = (wbf != nullptr);

    // layer 1: 64 -> 64 via MFMA (4 ntiles x 2 ksteps), weight frag feeds
    // both centroids' MFMAs. Reads precede in-place writes (same-wave DS
    // order; each wave owns its 16-row block in both phases).
    {
        bf16x8 a1f[2][2];
#pragma unroll
        for (int cc = 0; cc < 2; ++cc)
#pragma unroll
            for (int ks = 0; ks < 2; ++ks)
                a1f[cc][ks] = *(const bf16x8*)&feat[cc][arow * 72 + ks * 32 + quad * 8];

#pragma unroll
        for (int nt = 0; nt < 4; ++nt) {
            f32x4 acc0 = {0.f, 0.f, 0.f, 0.f};
            f32x4 acc1 = {0.f, 0.f, 0.f, 0.f};
#pragma unroll
            for (int ks = 0; ks < 2; ++ks) {
                int off = (nt * 16 + ln) * 64 + ks * 32 + quad * 8;
                bf16x8 bf;
                if (usebf) {
                    bf = *(const bf16x8*)&wbf[off];
                } else {
                    const float* wr = w1 + off;
                    float4 p = *(const float4*)wr;
                    float4 q = *(const float4*)(wr + 4);
                    bf = (bf16x8){f2bf(p.x), f2bf(p.y), f2bf(p.z), f2bf(p.w),
                                  f2bf(q.x), f2bf(q.y), f2bf(q.z), f2bf(q.w)};
                }
                acc0 = __builtin_amdgcn_mfma_f32_16x16x32_bf16(a1f[0][ks], bf, acc0, 0, 0, 0);
                acc1 = __builtin_amdgcn_mfma_f32_16x16x32_bf16(a1f[1][ks], bf, acc1, 0, 0, 0);
            }
            int o = nt * 16 + ln;
            float sc = scs[64 + o], of = ofs[64 + o];
#pragma unroll
            for (int reg = 0; reg < 4; ++reg) {
                float y0 = fmaxf(fmaf(acc0[reg], sc, of), 0.f);
                float y1 = fmaxf(fmaf(acc1[reg], sc, of), 0.f);
                feat[0][(16 * wq + quad * 4 + reg) * 72 + o] = f2bf(y0);
                feat[1][(16 * wq + quad * 4 + reg) * 72 + o] = f2bf(y1);
            }
        }
    }
    // no barrier: each wave reads back only its own m-tile rows

    // layer 2: 64 -> 128 via MFMA (8 ntiles x 2 ksteps) + fused k-max
    {
        bf16x8 a2f[2][2];
#pragma unroll
        for (int cc = 0; cc < 2; ++cc)
#pragma unroll
            for (int ks = 0; ks < 2; ++ks)
                a2f[cc][ks] = *(const bf16x8*)&feat[cc][arow * 72 + ks * 32 + quad * 8];

#pragma unroll
        for (int nt = 0; nt < 8; ++nt) {
            f32x4 acc0 = {0.f, 0.f, 0.f, 0.f};
            f32x4 acc1 = {0.f, 0.f, 0.f, 0.f};
#pragma unroll
            for (int ks = 0; ks < 2; ++ks) {
                int off = (nt * 16 + ln) * 64 + ks * 32 + quad * 8;
                bf16x8 bf;
                if (usebf) {
                    bf = *(const bf16x8*)&wbf[4096 + off];
                } else {
                    const float* wr = w2 + off;
                    float4 p = *(const float4*)wr;
                    float4 q = *(const float4*)(wr + 4);
                    bf = (bf16x8){f2bf(p.x), f2bf(p.y), f2bf(p.z), f2bf(p.w),
                                  f2bf(q.x), f2bf(q.y), f2bf(q.z), f2bf(q.w)};
                }
                acc0 = __builtin_amdgcn_mfma_f32_16x16x32_bf16(a2f[0][ks], bf, acc0, 0, 0, 0);
                acc1 = __builtin_amdgcn_mfma_f32_16x16x32_bf16(a2f[1][ks], bf, acc1, 0, 0, 0);
            }
            int o = nt * 16 + ln;
            float sc = scs[128 + o], of = ofs[128 + o];
            float m0_ = -1.f, m1_ = -1.f;
#pragma unroll
            for (int reg = 0; reg < 4; ++reg) {
                m0_ = fmaxf(m0_, fmaxf(fmaf(acc0[reg], sc, of), 0.f));
                m1_ = fmaxf(m1_, fmaxf(fmaf(acc1[reg], sc, of), 0.f));
            }
            m0_ = fmaxf(m0_, __shfl_xor(m0_, 16, 64));
            m0_ = fmaxf(m0_, __shfl_xor(m0_, 32, 64));
            m1_ = fmaxf(m1_, __shfl_xor(m1_, 16, 64));
            m1_ = fmaxf(m1_, __shfl_xor(m1_, 32, 64));
            if (lane < 16) {
                wmaxs[0][wq * 132 + o] = m0_;
                wmaxs[1][wq * 132 + o] = m1_;
            }
        }
    }
    __syncthreads();

    // final: max over the 4 waves' m-tiles, store new_points for both
    {
        int cc = t >> 7, ch = t & 127;
        float m = fmaxf(fmaxf(wmaxs[cc][0 * 132 + ch], wmaxs[cc][1 * 132 + ch]),
                        fmaxf(wmaxs[cc][2 * 132 + ch], wmaxs[cc][3 * 132 + ch]));
        out[OUT1 + (b * 128 + ch) * S_ + s0 + cc] = m;
    }
}

extern "C" void kernel_launch(void* const* d_in, const int* in_sizes, int n_in,
                              void* d_out, int out_size, void* d_ws, size_t ws_size,
                              hipStream_t stream) {
    const float* xyz  = (const float*)d_in[0];
    const float* pts  = (const float*)d_in[1];
    const int*   seed = (const int*)d_in[2];
    const float* w0 = (const float*)d_in[3];
    const float* b0 = (const float*)d_in[4];
    const float* g0 = (const float*)d_in[5];
    const float* be0 = (const float*)d_in[6];
    const float* m0 = (const float*)d_in[7];
    const float* v0 = (const float*)d_in[8];
    const float* w1 = (const float*)d_in[9];
    const float* b1 = (const float*)d_in[10];
    const float* g1 = (const float*)d_in[11];
    const float* be1 = (const float*)d_in[12];
    const float* m1 = (const float*)d_in[13];
    const float* v1 = (const float*)d_in[14];
    const float* w2 = (const float*)d_in[15];
    const float* b2 = (const float*)d_in[16];
    const float* g2 = (const float*)d_in[17];
    const float* be2 = (const float*)d_in[18];
    const float* m2 = (const float*)d_in[19];
    const float* v2 = (const float*)d_in[20];
    float* out = (float*)d_out;

    short* wbf = nullptr;
    if (ws_size >= 12288 * sizeof(short)) {
        wbf = (short*)d_ws;
        wconv_kernel<<<dim3(48), dim3(256), 0, stream>>>(w1, w2, wbf);
    }

    fps_kernel<<<dim3(B_), dim3(FPS_T), 0, stream>>>(xyz, out);
    down_kernel<<<dim3(B_ * S_ / 2), dim3(256), 0, stream>>>(xyz, pts, seed,
        w0, b0, g0, be0, m0, v0,
        w1, b1, g1, be1, m1, v1,
        w2, b2, g2, be2, m2, v2,
        out, wbf);
}